// Round 1
// baseline (48.855 us; speedup 1.0000x reference)
//
#include <hip/hip_runtime.h>
#include <math.h>

constexpr int NG    = 8192;   // genes
constexpr int NSETS = 256;    // M
constexpr int NB    = 32;     // batch
constexpr int TB    = 8;      // b's per block in main kernel

__device__ __forceinline__ float sigmoidf(float x) {
  return 1.0f / (1.0f + expf(-x));
}

// Per-set threshold: thr[m] = mean(sigmoid(W[m,:])) * 0.3
__global__ __launch_bounds__(256) void k_thr(const float* __restrict__ W,
                                             float* __restrict__ thr) {
  const int m = blockIdx.x;
  const float4* w4 = reinterpret_cast<const float4*>(W + (size_t)m * NG);
  float s = 0.f;
  for (int i = threadIdx.x; i < NG / 4; i += 256) {
    float4 v = w4[i];
    s += sigmoidf(v.x) + sigmoidf(v.y) + sigmoidf(v.z) + sigmoidf(v.w);
  }
  __shared__ float red[256];
  red[threadIdx.x] = s;
  __syncthreads();
  for (int off = 128; off > 0; off >>= 1) {
    if (threadIdx.x < off) red[threadIdx.x] += red[threadIdx.x + off];
    __syncthreads();
  }
  if (threadIdx.x == 0) thr[m] = (red[0] / (float)NG) * 0.3f;
}

// Scatter the cumsum coefficient back to original gene order:
// element at sorted position k contributes to (G-k) cumsum entries.
__global__ __launch_bounds__(256) void k_rank(const int* __restrict__ S,
                                              float* __restrict__ cf) {
  const int b = blockIdx.x;
  for (int k = threadIdx.x; k < NG; k += 256) {
    const int g = S[(size_t)b * NG + k];
    cf[(size_t)b * NG + g] = (float)(NG - k);
  }
}

// Main: out[b,m] = (Σw·c/(Σw+1e-10) - Σn·c/(Σn+1e-10)) / G
__global__ __launch_bounds__(256) void k_main(const float* __restrict__ R,
                                              const float* __restrict__ W,
                                              const float* __restrict__ thr,
                                              const float* __restrict__ cf,
                                              float* __restrict__ out) {
  const int m  = blockIdx.x;
  const int bg = blockIdx.y;
  const float tm = thr[m];
  const float4* w4 = reinterpret_cast<const float4*>(W + (size_t)m * NG);

  float sA[TB], sB[TB], sN[TB], sC[TB];
  #pragma unroll
  for (int i = 0; i < TB; ++i) { sA[i] = 0.f; sB[i] = 0.f; sN[i] = 0.f; sC[i] = 0.f; }

  for (int i = threadIdx.x; i < NG / 4; i += 256) {
    float4 wv = w4[i];
    float wtmp[4] = {wv.x, wv.y, wv.z, wv.w};
    float ind[4], neg[4];
    #pragma unroll
    for (int j = 0; j < 4; ++j) {
      float v = sigmoidf(wtmp[j]);
      v = (v < tm) ? v * 0.01f : v;        // _set_indicators where()
      ind[j] = v;
      neg[j] = (v < 0.1f) ? 1.f : 0.f;     // neg indicator
    }
    #pragma unroll
    for (int bl = 0; bl < TB; ++bl) {
      const int b = bg * TB + bl;
      float4 rv = reinterpret_cast<const float4*>(R  + (size_t)b * NG)[i];
      float4 cv = reinterpret_cast<const float4*>(cf + (size_t)b * NG)[i];
      float rr[4] = {rv.x, rv.y, rv.z, rv.w};
      float cc[4] = {cv.x, cv.y, cv.z, cv.w};
      #pragma unroll
      for (int j = 0; j < 4; ++j) {
        float x = rr[j] * ind[j];
        x = fminf(fmaxf(x, 1e-8f), 1e4f);
        float wq = __builtin_amdgcn_sqrtf(__builtin_amdgcn_sqrtf(x)); // x^0.25
        sA[bl] += wq;
        sB[bl] = fmaf(wq, cc[j], sB[bl]);
        sN[bl] += neg[j];
        sC[bl] = fmaf(neg[j], cc[j], sC[bl]);
      }
    }
  }

  // 64-lane butterfly reduce
  #pragma unroll
  for (int bl = 0; bl < TB; ++bl) {
    #pragma unroll
    for (int off = 32; off > 0; off >>= 1) {
      sA[bl] += __shfl_xor(sA[bl], off, 64);
      sB[bl] += __shfl_xor(sB[bl], off, 64);
      sN[bl] += __shfl_xor(sN[bl], off, 64);
      sC[bl] += __shfl_xor(sC[bl], off, 64);
    }
  }

  __shared__ float red[4][TB][4];
  const int wid  = threadIdx.x >> 6;
  const int lane = threadIdx.x & 63;
  if (lane == 0) {
    #pragma unroll
    for (int bl = 0; bl < TB; ++bl) {
      red[wid][bl][0] = sA[bl];
      red[wid][bl][1] = sB[bl];
      red[wid][bl][2] = sN[bl];
      red[wid][bl][3] = sC[bl];
    }
  }
  __syncthreads();
  if (threadIdx.x < TB) {
    const int bl = threadIdx.x;
    float a = 0.f, bb = 0.f, n = 0.f, c = 0.f;
    #pragma unroll
    for (int w = 0; w < 4; ++w) {
      a  += red[w][bl][0];
      bb += red[w][bl][1];
      n  += red[w][bl][2];
      c  += red[w][bl][3];
    }
    const float pos  = bb / (a + 1e-10f);
    const float negc = c  / (n + 1e-10f);   // n==0 -> c==0 -> 0, matches where()
    const int b = bg * TB + bl;
    out[(size_t)b * NSETS + m] = (pos - negc) * (1.0f / (float)NG);
  }
}

extern "C" void kernel_launch(void* const* d_in, const int* in_sizes, int n_in,
                              void* d_out, int out_size, void* d_ws, size_t ws_size,
                              hipStream_t stream) {
  const float* R = (const float*)d_in[0];
  const int*   S = (const int*)d_in[1];
  const float* W = (const float*)d_in[2];
  float* out = (float*)d_out;

  float* thr = (float*)d_ws;        // 256 floats
  float* cf  = thr + 256;           // 32*8192 floats (~1 MB total ws use)

  k_thr <<<dim3(NSETS), dim3(256), 0, stream>>>(W, thr);
  k_rank<<<dim3(NB),    dim3(256), 0, stream>>>(S, cf);
  k_main<<<dim3(NSETS, NB / TB), dim3(256), 0, stream>>>(R, W, thr, cf, out);
}